// Round 2
// baseline (1343.342 us; speedup 1.0000x reference)
//
#include <hip/hip_runtime.h>
#include <hip/hip_bf16.h>

#define B_  64
#define S_  128
#define WP_ 18
#define K_  3
#define E_  128
#define H_  256
#define L_  4
#define T_  50

typedef __hip_bfloat16 bf16;

__device__ __forceinline__ float b2f(bf16 x) { return __bfloat162float(x); }
__device__ __forceinline__ bf16  f2b(float x) { return __float2bfloat16(x); }

// ---------------------------------------------------------------- transpose (f32 -> bf16)
// dst[c*R + r] = (bf16)src[r*C + c]
__global__ void k_transpose(const float* __restrict__ src, bf16* __restrict__ dst,
                            int R, int C) {
    int i = blockIdx.x * 256 + threadIdx.x;
    if (i >= R * C) return;
    int r = i / C, c = i % C;
    dst[c * R + r] = f2b(src[i]);
}

// ---------------------------------------------------------------- char CNN
// one wave per (b,s) word; char_reprs[b,s,l] = max over 16 window positions
__global__ void k_charcnn(const int* __restrict__ char_ids,
                          const float* __restrict__ char_emb,
                          const float* __restrict__ cnn_w,
                          const float* __restrict__ cnn_b,
                          float* __restrict__ out_char) {
    const int CE_S = 132;   // padded stride
    const int W_S  = 388;
    __shared__ float ce[WP_ * 132];
    __shared__ float w[L_ * 388];
    __shared__ float bias[L_];
    int idx = blockIdx.x;            // b*S + s
    int t   = threadIdx.x;           // 0..63
    const int* ids = char_ids + idx * WP_;
    for (int i = t; i < WP_ * E_; i += 64) {
        int r = i >> 7, e = i & 127;
        ce[r * CE_S + e] = char_emb[ids[r] * E_ + e];
    }
    for (int i = t; i < L_ * K_ * E_; i += 64) {
        int r = i / (K_ * E_), e = i % (K_ * E_);
        w[r * W_S + e] = cnn_w[i];
    }
    if (t < L_) bias[t] = cnn_b[t];
    __syncthreads();
    int pos = t >> 2, c = t & 3;     // 16 positions x 4 channels
    float acc = 0.f;
    const float* wr = &w[c * W_S];
    #pragma unroll
    for (int i = 0; i < K_; ++i) {
        const float* cr = &ce[(pos + i) * CE_S];
        #pragma unroll 8
        for (int e = 0; e < E_; ++e) acc = fmaf(cr[e], wr[i * E_ + e], acc);
    }
    acc += bias[c];
    #pragma unroll
    for (int off = 4; off < 64; off <<= 1) acc = fmaxf(acc, __shfl_xor(acc, off));
    if (t < L_) out_char[idx * L_ + t] = acc;
}

// ---------------------------------------------------------------- input proj
// ig[s*B+b, j] = b[j] + sum_k we[b,s,k] * WihT[k, j]   (both directions)
__global__ void k_input_proj(const int* __restrict__ word_ids,
                             const float* __restrict__ word_emb,
                             const bf16* __restrict__ wihT_f, const float* __restrict__ b_f,
                             const bf16* __restrict__ wihT_b, const float* __restrict__ b_b,
                             bf16* __restrict__ ig_f, bf16* __restrict__ ig_b) {
    int dir = blockIdx.y;
    const bf16* wihT = dir ? wihT_b : wihT_f;
    const float* bb  = dir ? b_b    : b_f;
    bf16* ig         = dir ? ig_b   : ig_f;
    __shared__ float x[8][128];
    int t  = threadIdx.x;            // 0..255
    int r0 = blockIdx.x * 8;         // 8 rows (s*B+b) per block
    for (int i = t; i < 8 * 128; i += 256) {
        int rr = i >> 7, e = i & 127;
        int r = r0 + rr;
        int s = r >> 6, b = r & 63;              // r = s*B + b, B = 64
        int wid = word_ids[b * S_ + s];
        x[rr][e] = word_emb[(size_t)wid * E_ + e];
    }
    __syncthreads();
    int j = t;                                    // columns j, j+256, j+512, j+768
    float acc[4][8];
    #pragma unroll
    for (int cj = 0; cj < 4; ++cj) {
        float bv = bb[j + cj * 256];
        #pragma unroll
        for (int rr = 0; rr < 8; ++rr) acc[cj][rr] = bv;
    }
    for (int k = 0; k < 128; ++k) {
        float wv[4];
        #pragma unroll
        for (int cj = 0; cj < 4; ++cj) wv[cj] = b2f(wihT[k * 1024 + j + cj * 256]);
        #pragma unroll
        for (int rr = 0; rr < 8; ++rr) {
            float xv = x[rr][k];
            #pragma unroll
            for (int cj = 0; cj < 4; ++cj) acc[cj][rr] = fmaf(xv, wv[cj], acc[cj][rr]);
        }
    }
    #pragma unroll
    for (int cj = 0; cj < 4; ++cj)
        #pragma unroll
        for (int rr = 0; rr < 8; ++rr)
            ig[(size_t)(r0 + rr) * 1024 + j + cj * 256] = f2b(acc[cj][rr]);
}

// ---------------------------------------------------------------- recurrence
// one block per (batch, direction); h in LDS, c in registers of threads <256
__global__ __launch_bounds__(1024) void k_lstm_rec(
        const bf16* __restrict__ ig_f, const bf16* __restrict__ ig_b,
        const bf16* __restrict__ whhT_f, const bf16* __restrict__ whhT_b,
        float* __restrict__ hf, float* __restrict__ hb) {
    int b   = blockIdx.x & 63;
    int dir = blockIdx.x >> 6;
    const bf16* ig   = dir ? ig_b   : ig_f;
    const bf16* whhT = dir ? whhT_b : whhT_f;
    float* hs        = dir ? hb     : hf;
    __shared__ float h[256];
    __shared__ float zbuf[1024];
    int t = threadIdx.x;
    if (t < 256) h[t] = 0.f;
    float c = 0.f;
    __syncthreads();
    for (int step = 0; step < S_; ++step) {
        int s = dir ? (S_ - 1 - step) : step;
        const bf16* igrow = ig + ((size_t)s * B_ + b) * 1024;
        float z = b2f(igrow[t]);
        #pragma unroll 8
        for (int k = 0; k < 256; ++k)
            z = fmaf(h[k], b2f(whhT[k * 1024 + t]), z);
        zbuf[t] = z;
        __syncthreads();
        if (t < 256) {
            float zi = zbuf[t], zf = zbuf[t + 256], zg = zbuf[t + 512], zo = zbuf[t + 768];
            float si = 1.f / (1.f + expf(-zi));
            float sf = 1.f / (1.f + expf(-zf));
            float so = 1.f / (1.f + expf(-zo));
            float tg = tanhf(zg);
            c = sf * c + si * tg;
            float hn = so * tanhf(c);
            h[t] = hn;
            hs[((size_t)s * B_ + b) * 256 + t] = hn;
        }
        __syncthreads();
    }
}

// ---------------------------------------------------------------- tag linear
// tag[b][t][s] = out_b[t] + dot(concat(hf[s,b,:], hb[s,b,:]), out_w[t,:])
__global__ void k_tag_linear(const float* __restrict__ hf, const float* __restrict__ hb,
                             const float* __restrict__ out_w, const float* __restrict__ out_b,
                             float* __restrict__ tag) {
    int bs = blockIdx.x;             // b*S + s
    int b = bs >> 7, s = bs & 127;
    __shared__ float hv[512];
    int t = threadIdx.x;             // 0..63
    const float* hfr = hf + ((size_t)s * B_ + b) * 256;
    const float* hbr = hb + ((size_t)s * B_ + b) * 256;
    for (int i = t; i < 256; i += 64) { hv[i] = hfr[i]; hv[256 + i] = hbr[i]; }
    __syncthreads();
    if (t < T_) {
        float acc = out_b[t];
        #pragma unroll 8
        for (int k = 0; k < 512; ++k) acc = fmaf(hv[k], out_w[t * 512 + k], acc);
        tag[((size_t)b * T_ + t) * S_ + s] = acc;
    }
}

// ---------------------------------------------------------------- log_softmax over S (axis=1)
__global__ void k_log_softmax(const float* __restrict__ tag, float* __restrict__ out) {
    int wid  = (blockIdx.x * 256 + threadIdx.x) >> 6;   // one wave per (b,t)
    int lane = threadIdx.x & 63;
    if (wid >= B_ * T_) return;
    int b = wid / T_, t = wid % T_;
    const float* row = tag + (size_t)wid * S_;
    float v0 = row[lane], v1 = row[lane + 64];
    float m = fmaxf(v0, v1);
    #pragma unroll
    for (int off = 32; off; off >>= 1) m = fmaxf(m, __shfl_xor(m, off));
    float e = expf(v0 - m) + expf(v1 - m);
    #pragma unroll
    for (int off = 32; off; off >>= 1) e += __shfl_xor(e, off);
    float lse = m + logf(e);
    out[((size_t)b * S_ + lane)      * T_ + t] = v0 - lse;
    out[((size_t)b * S_ + lane + 64) * T_ + t] = v1 - lse;
}

// ---------------------------------------------------------------- launch
extern "C" void kernel_launch(void* const* d_in, const int* in_sizes, int n_in,
                              void* d_out, int out_size, void* d_ws, size_t ws_size,
                              hipStream_t stream) {
    const int*   char_ids = (const int*)d_in[0];
    const int*   word_ids = (const int*)d_in[1];
    const float* char_emb = (const float*)d_in[2];
    const float* word_emb = (const float*)d_in[3];
    const float* cnn_w    = (const float*)d_in[4];
    const float* cnn_b    = (const float*)d_in[5];
    const float* wih_f    = (const float*)d_in[6];
    const float* whh_f    = (const float*)d_in[7];
    const float* b_f      = (const float*)d_in[8];
    const float* wih_b    = (const float*)d_in[9];
    const float* whh_b    = (const float*)d_in[10];
    const float* b_b      = (const float*)d_in[11];
    const float* out_w    = (const float*)d_in[12];
    const float* out_b    = (const float*)d_in[13];
    float* out = (float*)d_out;
    char* ws   = (char*)d_ws;

    size_t o = 0;
    bf16* wihT_f = (bf16*)(ws + o); o += (size_t)128 * 1024 * 2;
    bf16* wihT_b = (bf16*)(ws + o); o += (size_t)128 * 1024 * 2;
    bf16* whhT_f = (bf16*)(ws + o); o += (size_t)256 * 1024 * 2;
    bf16* whhT_b = (bf16*)(ws + o); o += (size_t)256 * 1024 * 2;
    bf16* ig_f   = (bf16*)(ws + o); o += (size_t)S_ * B_ * 1024 * 2;
    bf16* ig_b   = (bf16*)(ws + o); o += (size_t)S_ * B_ * 1024 * 2;
    float* hf    = (float*)(ws + o); o += (size_t)S_ * B_ * 256 * 4;
    float* hb    = (float*)(ws + o); o += (size_t)S_ * B_ * 256 * 4;
    float* tag   = (float*)(ws + o); o += (size_t)B_ * T_ * S_ * 4;

    k_transpose<<<512, 256, 0, stream>>>(wih_f, wihT_f, 1024, 128);
    k_transpose<<<512, 256, 0, stream>>>(wih_b, wihT_b, 1024, 128);
    k_transpose<<<1024, 256, 0, stream>>>(whh_f, whhT_f, 1024, 256);
    k_transpose<<<1024, 256, 0, stream>>>(whh_b, whhT_b, 1024, 256);
    k_input_proj<<<dim3(1024, 2), 256, 0, stream>>>(word_ids, word_emb,
                                                    wihT_f, b_f, wihT_b, b_b, ig_f, ig_b);
    k_charcnn<<<B_ * S_, 64, 0, stream>>>(char_ids, char_emb, cnn_w, cnn_b,
                                          out + (size_t)B_ * S_ * T_);
    k_lstm_rec<<<128, 1024, 0, stream>>>(ig_f, ig_b, whhT_f, whhT_b, hf, hb);
    k_tag_linear<<<B_ * S_, 64, 0, stream>>>(hf, hb, out_w, out_b, tag);
    k_log_softmax<<<(B_ * T_ + 3) / 4, 256, 0, stream>>>(tag, out);
}

// Round 3
// 792.639 us; speedup vs baseline: 1.6948x; 1.6948x over previous
//
#include <hip/hip_runtime.h>
#include <hip/hip_bf16.h>

#define B_  64
#define S_  128
#define WP_ 18
#define K_  3
#define E_  128
#define H_  256
#define L_  4
#define T_  50

typedef __hip_bfloat16 bf16;

__device__ __forceinline__ float b2f(bf16 x) { return __bfloat162float(x); }
__device__ __forceinline__ bf16  f2b(float x) { return __float2bfloat16(x); }

__device__ __forceinline__ float fast_sigmoid(float x) {
    return 1.f / (1.f + __expf(-x));
}
__device__ __forceinline__ float fast_tanh(float x) {
    float a = fminf(fmaxf(2.f * x, -30.f), 30.f);
    float e = __expf(a);
    return (e - 1.f) / (e + 1.f);
}

// ---------------------------------------------------------------- transpose (f32 -> bf16)
// dst[c*R + r] = (bf16)src[r*C + c]    (used for Wih only)
__global__ void k_transpose(const float* __restrict__ src, bf16* __restrict__ dst,
                            int R, int C) {
    int i = blockIdx.x * 256 + threadIdx.x;
    if (i >= R * C) return;
    int r = i / C, c = i % C;
    dst[c * R + r] = f2b(src[i]);
}

// ---------------------------------------------------------------- pack Whh for the recurrence
// src: Whh [1024][256] row-major (f32). dst tile layout:
// dst[((jb*32 + kb)*64 + lane)*8 + e] = src[(jb*64+lane)*256 + kb*8 + e]  (bf16)
// so a wave's (64 lanes, column j = wave*64+lane) kb-th load is one coalesced 1KB b128.
__global__ void k_pack_whh(const float* __restrict__ src, bf16* __restrict__ dst) {
    int i = blockIdx.x * 256 + threadIdx.x;   // over 1024*256
    if (i >= 1024 * 256) return;
    int j = i >> 8, k = i & 255;
    int jb = j >> 6, lane = j & 63, kb = k >> 3, e = k & 7;
    dst[(((jb * 32 + kb) * 64 + lane) << 3) + e] = f2b(src[i]);
}

// ---------------------------------------------------------------- char CNN
__global__ void k_charcnn(const int* __restrict__ char_ids,
                          const float* __restrict__ char_emb,
                          const float* __restrict__ cnn_w,
                          const float* __restrict__ cnn_b,
                          float* __restrict__ out_char) {
    const int CE_S = 132;
    const int W_S  = 388;
    __shared__ float ce[WP_ * 132];
    __shared__ float w[L_ * 388];
    __shared__ float bias[L_];
    int idx = blockIdx.x;            // b*S + s
    int t   = threadIdx.x;           // 0..63
    const int* ids = char_ids + idx * WP_;
    for (int i = t; i < WP_ * E_; i += 64) {
        int r = i >> 7, e = i & 127;
        ce[r * CE_S + e] = char_emb[ids[r] * E_ + e];
    }
    for (int i = t; i < L_ * K_ * E_; i += 64) {
        int r = i / (K_ * E_), e = i % (K_ * E_);
        w[r * W_S + e] = cnn_w[i];
    }
    if (t < L_) bias[t] = cnn_b[t];
    __syncthreads();
    int pos = t >> 2, c = t & 3;     // 16 positions x 4 channels
    float acc = 0.f;
    const float* wr = &w[c * W_S];
    #pragma unroll
    for (int i = 0; i < K_; ++i) {
        const float* cr = &ce[(pos + i) * CE_S];
        #pragma unroll 8
        for (int e = 0; e < E_; ++e) acc = fmaf(cr[e], wr[i * E_ + e], acc);
    }
    acc += bias[c];
    #pragma unroll
    for (int off = 4; off < 64; off <<= 1) acc = fmaxf(acc, __shfl_xor(acc, off));
    if (t < L_) out_char[idx * L_ + t] = acc;
}

// ---------------------------------------------------------------- input proj
__global__ void k_input_proj(const int* __restrict__ word_ids,
                             const float* __restrict__ word_emb,
                             const bf16* __restrict__ wihT_f, const float* __restrict__ b_f,
                             const bf16* __restrict__ wihT_b, const float* __restrict__ b_b,
                             bf16* __restrict__ ig_f, bf16* __restrict__ ig_b) {
    int dir = blockIdx.y;
    const bf16* wihT = dir ? wihT_b : wihT_f;
    const float* bb  = dir ? b_b    : b_f;
    bf16* ig         = dir ? ig_b   : ig_f;
    __shared__ float x[8][128];
    int t  = threadIdx.x;            // 0..255
    int r0 = blockIdx.x * 8;         // 8 rows (s*B+b) per block
    for (int i = t; i < 8 * 128; i += 256) {
        int rr = i >> 7, e = i & 127;
        int r = r0 + rr;
        int s = r >> 6, b = r & 63;              // r = s*B + b, B = 64
        int wid = word_ids[b * S_ + s];
        x[rr][e] = word_emb[(size_t)wid * E_ + e];
    }
    __syncthreads();
    int j = t;
    float acc[4][8];
    #pragma unroll
    for (int cj = 0; cj < 4; ++cj) {
        float bv = bb[j + cj * 256];
        #pragma unroll
        for (int rr = 0; rr < 8; ++rr) acc[cj][rr] = bv;
    }
    for (int k = 0; k < 128; ++k) {
        float wv[4];
        #pragma unroll
        for (int cj = 0; cj < 4; ++cj) wv[cj] = b2f(wihT[k * 1024 + j + cj * 256]);
        #pragma unroll
        for (int rr = 0; rr < 8; ++rr) {
            float xv = x[rr][k];
            #pragma unroll
            for (int cj = 0; cj < 4; ++cj) acc[cj][rr] = fmaf(xv, wv[cj], acc[cj][rr]);
        }
    }
    #pragma unroll
    for (int cj = 0; cj < 4; ++cj)
        #pragma unroll
        for (int rr = 0; rr < 8; ++rr)
            ig[(size_t)(r0 + rr) * 1024 + j + cj * 256] = f2b(acc[cj][rr]);
}

// ---------------------------------------------------------------- recurrence
// one block per (batch, direction); 1024 threads, thread t owns column j=t.
// Weights pre-packed so each wave's kb-th load is one coalesced b128 (8 bf16).
__global__ __launch_bounds__(1024) void k_lstm_rec(
        const bf16* __restrict__ ig_f, const bf16* __restrict__ ig_b,
        const uint4* __restrict__ wp_f, const uint4* __restrict__ wp_b,
        float* __restrict__ hf, float* __restrict__ hb) {
    int b   = blockIdx.x & 63;
    int dir = blockIdx.x >> 6;
    const bf16* ig  = dir ? ig_b : ig_f;
    const uint4* wp = dir ? wp_b : wp_f;
    float* hs       = dir ? hb   : hf;
    __shared__ __align__(16) float h[256];
    __shared__ float zbuf[1024];
    int t = threadIdx.x;
    int w = t >> 6, lane = t & 63;
    const uint4* wrow = wp + ((w * 32) * 64 + lane);   // advance by 64 per kb
    if (t < 256) h[t] = 0.f;
    float c = 0.f;
    __syncthreads();
    for (int step = 0; step < S_; ++step) {
        int s = dir ? (S_ - 1 - step) : step;
        float z = b2f(ig[((size_t)s * B_ + b) * 1024 + t]);
        #pragma unroll 8
        for (int kb = 0; kb < 32; ++kb) {
            uint4 wv = wrow[kb * 64];
            float4 h0 = *(const float4*)&h[kb * 8];
            float4 h1 = *(const float4*)&h[kb * 8 + 4];
            z = fmaf(__uint_as_float(wv.x << 16),          h0.x, z);
            z = fmaf(__uint_as_float(wv.x & 0xffff0000u),  h0.y, z);
            z = fmaf(__uint_as_float(wv.y << 16),          h0.z, z);
            z = fmaf(__uint_as_float(wv.y & 0xffff0000u),  h0.w, z);
            z = fmaf(__uint_as_float(wv.z << 16),          h1.x, z);
            z = fmaf(__uint_as_float(wv.z & 0xffff0000u),  h1.y, z);
            z = fmaf(__uint_as_float(wv.w << 16),          h1.z, z);
            z = fmaf(__uint_as_float(wv.w & 0xffff0000u),  h1.w, z);
        }
        zbuf[t] = z;
        __syncthreads();
        if (t < 256) {
            float zi = zbuf[t], zf = zbuf[t + 256], zg = zbuf[t + 512], zo = zbuf[t + 768];
            float si = fast_sigmoid(zi);
            float sf = fast_sigmoid(zf);
            float so = fast_sigmoid(zo);
            float tg = fast_tanh(zg);
            c = sf * c + si * tg;
            float hn = so * fast_tanh(c);
            h[t] = hn;
            hs[((size_t)s * B_ + b) * 256 + t] = hn;
        }
        __syncthreads();
    }
}

// ---------------------------------------------------------------- tag linear
__global__ void k_tag_linear(const float* __restrict__ hf, const float* __restrict__ hb,
                             const float* __restrict__ out_w, const float* __restrict__ out_b,
                             float* __restrict__ tag) {
    int bs = blockIdx.x;             // b*S + s
    int b = bs >> 7, s = bs & 127;
    __shared__ float hv[512];
    int t = threadIdx.x;             // 0..63
    const float* hfr = hf + ((size_t)s * B_ + b) * 256;
    const float* hbr = hb + ((size_t)s * B_ + b) * 256;
    for (int i = t; i < 256; i += 64) { hv[i] = hfr[i]; hv[256 + i] = hbr[i]; }
    __syncthreads();
    if (t < T_) {
        float acc = out_b[t];
        #pragma unroll 8
        for (int k = 0; k < 512; ++k) acc = fmaf(hv[k], out_w[t * 512 + k], acc);
        tag[((size_t)b * T_ + t) * S_ + s] = acc;
    }
}

// ---------------------------------------------------------------- log_softmax over S (axis=1)
__global__ void k_log_softmax(const float* __restrict__ tag, float* __restrict__ out) {
    int wid  = (blockIdx.x * 256 + threadIdx.x) >> 6;   // one wave per (b,t)
    int lane = threadIdx.x & 63;
    if (wid >= B_ * T_) return;
    int b = wid / T_, t = wid % T_;
    const float* row = tag + (size_t)wid * S_;
    float v0 = row[lane], v1 = row[lane + 64];
    float m = fmaxf(v0, v1);
    #pragma unroll
    for (int off = 32; off; off >>= 1) m = fmaxf(m, __shfl_xor(m, off));
    float e = expf(v0 - m) + expf(v1 - m);
    #pragma unroll
    for (int off = 32; off; off >>= 1) e += __shfl_xor(e, off);
    float lse = m + logf(e);
    out[((size_t)b * S_ + lane)      * T_ + t] = v0 - lse;
    out[((size_t)b * S_ + lane + 64) * T_ + t] = v1 - lse;
}

// ---------------------------------------------------------------- launch
extern "C" void kernel_launch(void* const* d_in, const int* in_sizes, int n_in,
                              void* d_out, int out_size, void* d_ws, size_t ws_size,
                              hipStream_t stream) {
    const int*   char_ids = (const int*)d_in[0];
    const int*   word_ids = (const int*)d_in[1];
    const float* char_emb = (const float*)d_in[2];
    const float* word_emb = (const float*)d_in[3];
    const float* cnn_w    = (const float*)d_in[4];
    const float* cnn_b    = (const float*)d_in[5];
    const float* wih_f    = (const float*)d_in[6];
    const float* whh_f    = (const float*)d_in[7];
    const float* b_f      = (const float*)d_in[8];
    const float* wih_b    = (const float*)d_in[9];
    const float* whh_b    = (const float*)d_in[10];
    const float* b_b      = (const float*)d_in[11];
    const float* out_w    = (const float*)d_in[12];
    const float* out_b    = (const float*)d_in[13];
    float* out = (float*)d_out;
    char* ws   = (char*)d_ws;

    size_t o = 0;
    bf16* wihT_f = (bf16*)(ws + o); o += (size_t)128 * 1024 * 2;
    bf16* wihT_b = (bf16*)(ws + o); o += (size_t)128 * 1024 * 2;
    bf16* wp_f   = (bf16*)(ws + o); o += (size_t)256 * 1024 * 2;
    bf16* wp_b   = (bf16*)(ws + o); o += (size_t)256 * 1024 * 2;
    bf16* ig_f   = (bf16*)(ws + o); o += (size_t)S_ * B_ * 1024 * 2;
    bf16* ig_b   = (bf16*)(ws + o); o += (size_t)S_ * B_ * 1024 * 2;
    float* hf    = (float*)(ws + o); o += (size_t)S_ * B_ * 256 * 4;
    float* hb    = (float*)(ws + o); o += (size_t)S_ * B_ * 256 * 4;
    float* tag   = (float*)(ws + o); o += (size_t)B_ * T_ * S_ * 4;

    k_transpose<<<512, 256, 0, stream>>>(wih_f, wihT_f, 1024, 128);
    k_transpose<<<512, 256, 0, stream>>>(wih_b, wihT_b, 1024, 128);
    k_pack_whh<<<1024, 256, 0, stream>>>(whh_f, wp_f);
    k_pack_whh<<<1024, 256, 0, stream>>>(whh_b, wp_b);
    k_input_proj<<<dim3(1024, 2), 256, 0, stream>>>(word_ids, word_emb,
                                                    wihT_f, b_f, wihT_b, b_b, ig_f, ig_b);
    k_charcnn<<<B_ * S_, 64, 0, stream>>>(char_ids, char_emb, cnn_w, cnn_b,
                                          out + (size_t)B_ * S_ * T_);
    k_lstm_rec<<<128, 1024, 0, stream>>>(ig_f, ig_b, (const uint4*)wp_f, (const uint4*)wp_b,
                                         hf, hb);
    k_tag_linear<<<B_ * S_, 64, 0, stream>>>(hf, hb, out_w, out_b, tag);
    k_log_softmax<<<(B_ * T_ + 3) / 4, 256, 0, stream>>>(tag, out);
}